// Round 1
// baseline (58925.055 us; speedup 1.0000x reference)
//
#include <hip/hip_runtime.h>

#define NSAMP 16384
#define NSTEP 32

typedef __attribute__((ext_vector_type(8))) short bf16x8;
typedef __attribute__((ext_vector_type(4))) short short4v;
typedef __attribute__((ext_vector_type(4))) float f32x4;

__device__ __forceinline__ unsigned short f2bf(float f) {
    unsigned int u = __float_as_uint(f);
    u += 0x7FFFu + ((u >> 16) & 1u);
    return (unsigned short)(u >> 16);
}
__device__ __forceinline__ float bf2fs(short h) {
    return __uint_as_float(((unsigned int)(unsigned short)h) << 16);
}

// ---------------- prep: pack weights to bf16 in d_ws ----------------
// ws layout (shorts):
//   [0,      65536)  W2 frag-packed for 16x16x32 mfma A-operand
//   [65536, 131072)  W3 frag-packed
//   [131072,147456)  W1T [i<64][k<256]
//   [147456,163840)  W4  [i<64][k<256] (row-major bf16 copy)
//   [163840,180224)  W1  [k<256][i<64] (row-major bf16 copy)
__global__ void prep_kernel(const float* __restrict__ W1, const float* __restrict__ W2,
                            const float* __restrict__ W3, const float* __restrict__ W4,
                            unsigned short* __restrict__ ws) {
    int j = blockIdx.x * blockDim.x + threadIdx.x;   // 0..65535
    if (j < 65536) {
        int e = j & 7, l = (j >> 3) & 63, s = (j >> 9) & 1, ks = (j >> 10) & 7, w = j >> 13;
        int m = (w << 5) + (s << 4) + (l & 15);          // output row
        int k = (ks << 5) + ((l >> 4) << 3) + e;         // K index
        ws[j]         = f2bf(W2[m * 256 + k]);
        ws[65536 + j] = f2bf(W3[m * 256 + k]);
    }
    if (j < 16384) {
        int i = j >> 8, k = j & 255;
        ws[131072 + j] = f2bf(W1[k * 64 + i]);   // W1T[i][k]
        ws[147456 + j] = f2bf(W4[j]);            // W4[i][k]
        ws[163840 + j] = f2bf(W1[j]);            // W1[k][i]
    }
}

// ---------------- main persistent-integration kernel ----------------
// one block = one sample; 8 waves; W2/W3 mfma fragments register-resident.
// XT (LDS, transposed, padded stride 264): cols 0..63 = tangent matrix A^T,
// col 64 = forward h column, col 65 = always-zero (broadcast source for the
// padding columns of the fused forward n-tile).

#define GEMM_LOOP(WF)                                                                   \
    _Pragma("unroll")                                                                   \
    for (int ks = 0; ks < 8; ++ks) {                                                    \
        const int kr = (ks << 5) + kband;                                               \
        bf16x8 bfr[5];                                                                  \
        _Pragma("unroll")                                                               \
        for (int ns = 0; ns < 4; ++ns)                                                  \
            bfr[ns] = *(const bf16x8*)&XT[((ns << 4) + lm) * 264 + kr];                 \
        bfr[4] = *(const bf16x8*)&XT[c64 * 264 + kr];                                   \
        _Pragma("unroll")                                                               \
        for (int ms = 0; ms < 2; ++ms) {                                                \
            _Pragma("unroll")                                                           \
            for (int ns = 0; ns < 5; ++ns)                                              \
                acc[ms][ns] = __builtin_amdgcn_mfma_f32_16x16x32_bf16(                  \
                    WF[ks][ms], bfr[ns], acc[ms][ns], 0, 0, 0);                         \
        }                                                                               \
    }

__launch_bounds__(512, 2)
__global__ void cnf_kernel(const float* __restrict__ zin,
                           const float* __restrict__ b1g, const float* __restrict__ b2g,
                           const float* __restrict__ b3g, const float* __restrict__ b4g,
                           const unsigned short* __restrict__ ws,
                           float* __restrict__ out)
{
    __shared__ __align__(16) unsigned short XT[66 * 264];    // 34.8 KB
    __shared__ __align__(16) unsigned short W1T[64 * 264];   // 33.8 KB  [i][k]
    __shared__ __align__(16) unsigned short W4L[64 * 264];   // 33.8 KB  [i][k]
    __shared__ __align__(16) unsigned short W1R[256 * 72];   // 36.9 KB  [k][i]
    __shared__ __align__(16) float dvec[256];
    __shared__ __align__(16) float hvec[256];
    __shared__ __align__(16) float hpart[512];
    __shared__ __align__(16) float dzp[256];
    __shared__ __align__(16) float zb[64];
    __shared__ __align__(16) float zcur[64];
    __shared__ __align__(16) float ka[64];
    __shared__ __align__(16) float b1l[256], b2l[256], b3l[256], b4l[64];
    __shared__ float wred[8];
    __shared__ float misc[2];   // [0]=ka_logp, [1]=logp

    const int tid = threadIdx.x;
    const int w = tid >> 6;
    const int l = tid & 63;
    const int lm = l & 15;
    const int c64 = 64 + (lm ? 1 : 0);
    const int bid = blockIdx.x;
    const int r0 = (w << 5) + ((l >> 4) << 2);   // wave row base + lane row group
    const int kband = (l >> 4) << 3;
    const float DT = -1.0f / 32.0f;

    // ---- register-resident W2/W3 fragments ----
    bf16x8 w2f[8][2], w3f[8][2];
    {
        const bf16x8* w2g = (const bf16x8*)ws;
        const bf16x8* w3g = w2g + 8192;
#pragma unroll
        for (int ks = 0; ks < 8; ++ks)
#pragma unroll
            for (int s = 0; s < 2; ++s) {
                int idx = (((w << 3) + ks) * 2 + s) * 64 + l;
                w2f[ks][s] = w2g[idx];
                w3f[ks][s] = w3g[idx];
            }
    }
    // ---- LDS init ----
    for (int c = tid; c < 2048; c += 512) {
        int i = c >> 5, k0 = (c & 31) << 3;
        *(bf16x8*)&W1T[i * 264 + k0] = *(const bf16x8*)&ws[131072 + i * 256 + k0];
        *(bf16x8*)&W4L[i * 264 + k0] = *(const bf16x8*)&ws[147456 + i * 256 + k0];
    }
    for (int c = tid; c < 2048; c += 512) {
        int k = c >> 3, i0 = (c & 7) << 3;
        *(bf16x8*)&W1R[k * 72 + i0] = *(const bf16x8*)&ws[163840 + k * 64 + i0];
    }
    for (int c = tid; c < (66 * 264 / 2); c += 512) ((unsigned int*)XT)[c] = 0u;
    for (int c = tid; c < 256; c += 512) { b1l[c] = b1g[c]; b2l[c] = b2g[c]; b3l[c] = b3g[c]; }
    if (tid < 64) {
        b4l[tid] = b4g[tid];
        float z = zin[bid * 64 + tid];
        zb[tid] = z; zcur[tid] = z;
    }
    if (tid == 0) { misc[0] = 0.f; misc[1] = 0.f; }
    __syncthreads();

    for (int it = 0; it < NSTEP * 4; ++it) {
        const int e = it & 3;

        // ---- phase 1a: h1 = tanh(W1 z + b1), d1 ----
        {
            int k = tid & 255, half = tid >> 8;
            const unsigned short* wr = &W1R[k * 72 + (half << 5)];
            const float* zc = &zcur[half << 5];
            float a = 0.f;
#pragma unroll
            for (int c = 0; c < 4; ++c) {
                bf16x8 wv = *(const bf16x8*)&wr[c * 8];
                float4 z0 = *(const float4*)&zc[c * 8];
                float4 z1 = *(const float4*)&zc[c * 8 + 4];
                a += bf2fs(wv[0]) * z0.x + bf2fs(wv[1]) * z0.y + bf2fs(wv[2]) * z0.z + bf2fs(wv[3]) * z0.w;
                a += bf2fs(wv[4]) * z1.x + bf2fs(wv[5]) * z1.y + bf2fs(wv[6]) * z1.z + bf2fs(wv[7]) * z1.w;
            }
            hpart[tid] = a;
        }
        __syncthreads();
        if (tid < 256) {
            float h = tanhf(hpart[tid] + hpart[256 + tid] + b1l[tid]);
            dvec[tid] = 1.f - h * h;
            XT[64 * 264 + tid] = f2bf(h);
        }
        __syncthreads();
        // ---- phase 1b: A1^T[i][k] = d1[k]*W1T[i][k] ----
        {
            int i = tid >> 3, k0 = (tid & 7) << 5;
#pragma unroll
            for (int c = 0; c < 4; ++c) {
                int kk = k0 + c * 8;
                bf16x8 wv = *(const bf16x8*)&W1T[i * 264 + kk];
                float4 d0 = *(const float4*)&dvec[kk];
                float4 d1_ = *(const float4*)&dvec[kk + 4];
                bf16x8 o;
                o[0] = (short)f2bf(bf2fs(wv[0]) * d0.x);
                o[1] = (short)f2bf(bf2fs(wv[1]) * d0.y);
                o[2] = (short)f2bf(bf2fs(wv[2]) * d0.z);
                o[3] = (short)f2bf(bf2fs(wv[3]) * d0.w);
                o[4] = (short)f2bf(bf2fs(wv[4]) * d1_.x);
                o[5] = (short)f2bf(bf2fs(wv[5]) * d1_.y);
                o[6] = (short)f2bf(bf2fs(wv[6]) * d1_.z);
                o[7] = (short)f2bf(bf2fs(wv[7]) * d1_.w);
                *(bf16x8*)&XT[i * 264 + kk] = o;
            }
        }
        __syncthreads();

        // ---- GEMM1: [A2_raw | y2] = W2 @ [A1 | h1 | 0] ----
        f32x4 acc[2][5];
#pragma unroll
        for (int ms = 0; ms < 2; ++ms)
#pragma unroll
            for (int ns = 0; ns < 5; ++ns) acc[ms][ns] = (f32x4){0.f, 0.f, 0.f, 0.f};
        GEMM_LOOP(w2f)
        __syncthreads();   // all XT reads done
        // epi 2a: h2/d2 from column 64
        if (lm == 0) {
#pragma unroll
            for (int ms = 0; ms < 2; ++ms) {
                int rb = r0 + (ms << 4);
#pragma unroll
                for (int rg = 0; rg < 4; ++rg) {
                    int r = rb + rg;
                    float h = tanhf(acc[ms][4][rg] + b2l[r]);
                    dvec[r] = 1.f - h * h;
                    XT[64 * 264 + r] = f2bf(h);
                }
            }
        }
        __syncthreads();
        // epi 2b: A2^T[col][r] = d2[r]*Y[r][col]
#pragma unroll
        for (int ms = 0; ms < 2; ++ms) {
            int rb = r0 + (ms << 4);
            float4 dv = *(const float4*)&dvec[rb];
#pragma unroll
            for (int ns = 0; ns < 4; ++ns) {
                int col = (ns << 4) + lm;
                short4v o;
                o[0] = (short)f2bf(acc[ms][ns][0] * dv.x);
                o[1] = (short)f2bf(acc[ms][ns][1] * dv.y);
                o[2] = (short)f2bf(acc[ms][ns][2] * dv.z);
                o[3] = (short)f2bf(acc[ms][ns][3] * dv.w);
                *(short4v*)&XT[col * 264 + rb] = o;
            }
        }
        __syncthreads();

        // ---- GEMM2: [A3_raw | y3] = W3 @ [A2 | h2 | 0] ----
#pragma unroll
        for (int ms = 0; ms < 2; ++ms)
#pragma unroll
            for (int ns = 0; ns < 5; ++ns) acc[ms][ns] = (f32x4){0.f, 0.f, 0.f, 0.f};
        GEMM_LOOP(w3f)
        __syncthreads();
        // epi 3a: h3/d3
        if (lm == 0) {
#pragma unroll
            for (int ms = 0; ms < 2; ++ms) {
                int rb = r0 + (ms << 4);
#pragma unroll
                for (int rg = 0; rg < 4; ++rg) {
                    int r = rb + rg;
                    float h = tanhf(acc[ms][4][rg] + b3l[r]);
                    hvec[r] = h;
                    dvec[r] = 1.f - h * h;
                }
            }
        }
        __syncthreads();
        // epi 3b: div partials (fused A3 epilogue) + dz partials
        {
            float p = 0.f;
#pragma unroll
            for (int ms = 0; ms < 2; ++ms) {
                int rb = r0 + (ms << 4);
                float4 dv = *(const float4*)&dvec[rb];
#pragma unroll
                for (int ns = 0; ns < 4; ++ns) {
                    int col = (ns << 4) + lm;
                    short4v wv = *(const short4v*)&W4L[col * 264 + rb];
                    p += acc[ms][ns][0] * dv.x * bf2fs(wv[0]);
                    p += acc[ms][ns][1] * dv.y * bf2fs(wv[1]);
                    p += acc[ms][ns][2] * dv.z * bf2fs(wv[2]);
                    p += acc[ms][ns][3] * dv.w * bf2fs(wv[3]);
                }
            }
#pragma unroll
            for (int o = 32; o; o >>= 1) p += __shfl_xor(p, o, 64);
            if (l == 0) wred[w] = p;
        }
        if (tid < 256) {   // dz[i] partial over k-chunk
            int i = tid & 63, ch = tid >> 6;
            const unsigned short* wr = &W4L[i * 264 + (ch << 6)];
            const float* hv = &hvec[ch << 6];
            float s = 0.f;
#pragma unroll
            for (int c = 0; c < 8; ++c) {
                bf16x8 wv = *(const bf16x8*)&wr[c * 8];
                float4 h0 = *(const float4*)&hv[c * 8];
                float4 h1 = *(const float4*)&hv[c * 8 + 4];
                s += bf2fs(wv[0]) * h0.x + bf2fs(wv[1]) * h0.y + bf2fs(wv[2]) * h0.z + bf2fs(wv[3]) * h0.w;
                s += bf2fs(wv[4]) * h1.x + bf2fs(wv[5]) * h1.y + bf2fs(wv[6]) * h1.z + bf2fs(wv[7]) * h1.w;
            }
            dzp[(ch << 6) + i] = s;
        }
        __syncthreads();

        // ---- RK4 bookkeeping ----
        if (tid < 64) {
            float div = wred[0] + wred[1] + wred[2] + wred[3] + wred[4] + wred[5] + wred[6] + wred[7];
            float dz = dzp[tid] + dzp[64 + tid] + dzp[128 + tid] + dzp[192 + tid] + b4l[tid];
            float wgt = (e == 0 || e == 3) ? 1.f : 2.f;
            float kav = (e == 0) ? dz : ka[tid] + wgt * dz;
            ka[tid] = kav;
            if (e < 3) {
                float cc = (e == 2) ? 1.0f : 0.5f;
                zcur[tid] = zb[tid] + cc * DT * dz;
            } else {
                float nz = zb[tid] + (DT / 6.0f) * kav;
                zb[tid] = nz; zcur[tid] = nz;
            }
            if (tid == 0) {
                float klv = -div;
                float kalv = (e == 0) ? klv : misc[0] + wgt * klv;
                misc[0] = kalv;
                if (e == 3) misc[1] += (DT / 6.0f) * kalv;
            }
        }
        __syncthreads();
    }

    if (tid < 64) out[bid * 64 + tid] = zb[tid];
    if (tid == 0) out[NSAMP * 64 + bid] = misc[1];
}

extern "C" void kernel_launch(void* const* d_in, const int* in_sizes, int n_in,
                              void* d_out, int out_size, void* d_ws, size_t ws_size,
                              hipStream_t stream) {
    const float* z  = (const float*)d_in[0];
    const float* W1 = (const float*)d_in[1];
    const float* b1 = (const float*)d_in[2];
    const float* W2 = (const float*)d_in[3];
    const float* b2 = (const float*)d_in[4];
    const float* W3 = (const float*)d_in[5];
    const float* b3 = (const float*)d_in[6];
    const float* W4 = (const float*)d_in[7];
    const float* b4 = (const float*)d_in[8];
    unsigned short* ws = (unsigned short*)d_ws;
    float* out = (float*)d_out;

    hipLaunchKernelGGL(prep_kernel, dim3(256), dim3(256), 0, stream, W1, W2, W3, W4, ws);
    hipLaunchKernelGGL(cnf_kernel, dim3(NSAMP), dim3(512), 0, stream, z, b1, b2, b3, b4, ws, out);
}

// Round 3
// 46729.166 us; speedup vs baseline: 1.2610x; 1.2610x over previous
//
#include <hip/hip_runtime.h>

#define NSAMP 16384
#define NSTEP 32

typedef __attribute__((ext_vector_type(8))) short bf16x8;
typedef __attribute__((ext_vector_type(4))) short short4v;
typedef __attribute__((ext_vector_type(4))) float f32x4;
typedef __attribute__((ext_vector_type(2))) unsigned int uint2v;
typedef __attribute__((ext_vector_type(4))) unsigned int uint4v;

__device__ __forceinline__ unsigned short f2bf(float f) {
    unsigned int u = __float_as_uint(f);
    u += 0x7FFFu + ((u >> 16) & 1u);
    return (unsigned short)(u >> 16);
}
__device__ __forceinline__ float bf2fs(short h) {
    return __uint_as_float(((unsigned int)(unsigned short)h) << 16);
}
__device__ __forceinline__ unsigned int cvtpk(float a, float b) {
    unsigned int r;
    asm("v_cvt_pk_bf16_f32 %0, %1, %2" : "=v"(r) : "v"(a), "v"(b));
    return r;
}
__device__ __forceinline__ float ftanh(float x) {
    float e = __expf(2.0f * x);
    return 1.0f - __fdividef(2.0f, e + 1.0f);
}

// ---------------- prep: pack weights to bf16 in d_ws ----------------
// ws layout (shorts):
//   [0,      65536)  W2 frag-packed (16x16x32 mfma A-operand, 8 waves x 8ks x 2ms)
//   [65536, 131072)  W3 frag-packed
//   [131072,147456)  W1T [i<64][k<256]
//   [147456,163840)  W4  [i<64][k<256]
//   [163840,180224)  W1 frag-packed (8 waves x 2ks x 2ms) for the z-MFMA
__global__ void prep_kernel(const float* __restrict__ W1, const float* __restrict__ W2,
                            const float* __restrict__ W3, const float* __restrict__ W4,
                            unsigned short* __restrict__ ws) {
    int j = blockIdx.x * blockDim.x + threadIdx.x;   // 0..65535
    if (j < 65536) {
        int e = j & 7, l = (j >> 3) & 63, s = (j >> 9) & 1, ks = (j >> 10) & 7, w = j >> 13;
        int m = (w << 5) + (s << 4) + (l & 15);
        int k = (ks << 5) + ((l >> 4) << 3) + e;
        ws[j]         = f2bf(W2[m * 256 + k]);
        ws[65536 + j] = f2bf(W3[m * 256 + k]);
    }
    if (j < 16384) {
        int i = j >> 8, k = j & 255;
        ws[131072 + j] = f2bf(W1[k * 64 + i]);   // W1T[i][k]
        ws[147456 + j] = f2bf(W4[j]);            // W4[i][k]
        int e = j & 7, l = (j >> 3) & 63, ms = (j >> 9) & 1, ks = (j >> 10) & 1, w = j >> 11;
        int m = (w << 5) + (ms << 4) + (l & 15);
        int i2 = (ks << 5) + ((l >> 4) << 3) + e;
        ws[163840 + j] = f2bf(W1[m * 64 + i2]);  // W1 A-frags (K=64)
    }
}

// ---------------- main persistent-integration kernel ----------------
// one block = TWO samples; 8 waves; W1/W2/W3 mfma A-fragments register-resident.
// XT rows (stride 264): 0-63 = tangent^T s0, 64-127 = tangent^T s1,
//   128/129 = h1 s0/s1, 130/131 = h2 s0/s1.
// GEMMs split into pass A (s0 tiles + parity h-tile) and pass B (s1 tiles),
// with epilogue-of-previous-pass overlapping the next pass's MFMA phase.

#define ZERO5()                                                              \
    _Pragma("unroll") for (int ms = 0; ms < 2; ++ms)                         \
    _Pragma("unroll") for (int ns = 0; ns < 5; ++ns)                         \
        acc[ms][ns] = (f32x4){0.f, 0.f, 0.f, 0.f};

#define ZERO4()                                                              \
    _Pragma("unroll") for (int ms = 0; ms < 2; ++ms)                         \
    _Pragma("unroll") for (int ns = 0; ns < 4; ++ns)                         \
        acc[ms][ns] = (f32x4){0.f, 0.f, 0.f, 0.f};

#define GEMM_PASS_A(WF, HBASE)                                               \
    __builtin_amdgcn_s_setprio(1);                                           \
    _Pragma("unroll") for (int ks = 0; ks < 8; ++ks) {                       \
        const int kr = (ks << 5) + kband;                                    \
        bf16x8 bfr[5];                                                       \
        _Pragma("unroll") for (int ns = 0; ns < 4; ++ns)                     \
            bfr[ns] = *(const bf16x8*)&XT[((ns << 4) + lm) * 264 + kr];      \
        bfr[4] = *(const bf16x8*)&XT[(HBASE + (lm & 1)) * 264 + kr];         \
        _Pragma("unroll") for (int ms = 0; ms < 2; ++ms)                     \
        _Pragma("unroll") for (int ns = 0; ns < 5; ++ns)                     \
            acc[ms][ns] = __builtin_amdgcn_mfma_f32_16x16x32_bf16(           \
                WF[ks][ms], bfr[ns], acc[ms][ns], 0, 0, 0);                  \
    }                                                                        \
    __builtin_amdgcn_s_setprio(0);

#define GEMM_PASS_B(WF)                                                      \
    __builtin_amdgcn_s_setprio(1);                                           \
    _Pragma("unroll") for (int ks = 0; ks < 8; ++ks) {                       \
        const int kr = (ks << 5) + kband;                                    \
        bf16x8 bfr[4];                                                       \
        _Pragma("unroll") for (int ns = 0; ns < 4; ++ns)                     \
            bfr[ns] = *(const bf16x8*)&XT[(((ns + 4) << 4) + lm) * 264 + kr];\
        _Pragma("unroll") for (int ms = 0; ms < 2; ++ms)                     \
        _Pragma("unroll") for (int ns = 0; ns < 4; ++ns)                     \
            acc[ms][ns] = __builtin_amdgcn_mfma_f32_16x16x32_bf16(           \
                WF[ks][ms], bfr[ns], acc[ms][ns], 0, 0, 0);                  \
    }                                                                        \
    __builtin_amdgcn_s_setprio(0);

__launch_bounds__(512, 2)
__global__ void cnf_kernel(const float* __restrict__ zin,
                           const float* __restrict__ b1g, const float* __restrict__ b2g,
                           const float* __restrict__ b3g, const float* __restrict__ b4g,
                           const unsigned short* __restrict__ ws,
                           float* __restrict__ out)
{
    __shared__ __align__(16) unsigned short XT[132 * 264];   // 69.7 KB
    __shared__ __align__(16) unsigned short W1T[64 * 264];   // 33.8 KB  [i][k]
    __shared__ __align__(16) unsigned short W4L[64 * 264];   // 33.8 KB  [i][k]
    __shared__ __align__(16) unsigned short ZBT[16 * 72];    // 2.3 KB (rows 2-15 zero)
    __shared__ __align__(16) float dvec1[2 * 256];
    __shared__ __align__(16) float hvec[2 * 256];
    __shared__ __align__(16) float dzp[2 * 256];
    __shared__ __align__(16) float b1l[256], b2l[256], b3l[256], b4l[64];
    __shared__ __align__(16) float zbv[2 * 64];
    __shared__ __align__(16) float kav[2 * 64];
    __shared__ float wredp[16];
    __shared__ float misc[4];   // [0..1]=ka_logp per s, [2..3]=logp per s

    const int tid = threadIdx.x;
    const int w = tid >> 6;
    const int l = tid & 63;
    const int lm = l & 15;
    const int bid = blockIdx.x;
    const int r0 = (w << 5) + ((l >> 4) << 2);
    const int kband = (l >> 4) << 3;
    const float DT = -1.0f / 32.0f;

    // ---- register-resident weight fragments ----
    bf16x8 w2f[8][2], w3f[8][2], w1f[2][2];
    {
        const bf16x8* w2g = (const bf16x8*)ws;
        const bf16x8* w3g = w2g + 8192;
        const bf16x8* w1g = (const bf16x8*)(ws + 163840);
#pragma unroll
        for (int ks = 0; ks < 8; ++ks)
#pragma unroll
            for (int s = 0; s < 2; ++s) {
                int idx = (((w << 3) + ks) * 2 + s) * 64 + l;
                w2f[ks][s] = w2g[idx];
                w3f[ks][s] = w3g[idx];
            }
#pragma unroll
        for (int ks = 0; ks < 2; ++ks)
#pragma unroll
            for (int ms = 0; ms < 2; ++ms)
                w1f[ks][ms] = w1g[(((w << 1) + ks) * 2 + ms) * 64 + l];
    }
    // ---- LDS init ----
    for (int c = tid; c < 2048; c += 512) {
        int i = c >> 5, k0 = (c & 31) << 3;
        *(bf16x8*)&W1T[i * 264 + k0] = *(const bf16x8*)&ws[131072 + i * 256 + k0];
        *(bf16x8*)&W4L[i * 264 + k0] = *(const bf16x8*)&ws[147456 + i * 256 + k0];
    }
    for (int c = 144 + tid; c < 1152; c += 512) ZBT[c] = 0;   // zero rows 2-15
    for (int c = tid; c < 256; c += 512) { b1l[c] = b1g[c]; b2l[c] = b2g[c]; b3l[c] = b3g[c]; }
    if (tid < 128) {
        const int s = tid >> 6, i = tid & 63;
        if (s == 0) b4l[i] = b4g[i];
        float z = zin[(bid * 2 + s) * 64 + i];
        zbv[tid] = z;
        ZBT[s * 72 + i] = f2bf(z);
    }
    if (tid < 2) { misc[tid] = 0.f; misc[2 + tid] = 0.f; }
    __syncthreads();

    for (int it = 0; it < NSTEP * 4; ++it) {
        const int e = it & 3;
        f32x4 acc[2][5];
        float d2loc[2][4], d3loc[2][4];
        float p0;

        // ---- P1: z-MFMA (h1 for both samples) ----
        {
            f32x4 az[2];
            az[0] = (f32x4){0.f, 0.f, 0.f, 0.f};
            az[1] = (f32x4){0.f, 0.f, 0.f, 0.f};
#pragma unroll
            for (int ks = 0; ks < 2; ++ks) {
                const bf16x8 zf = *(const bf16x8*)&ZBT[lm * 72 + (ks << 5) + kband];
#pragma unroll
                for (int ms = 0; ms < 2; ++ms)
                    az[ms] = __builtin_amdgcn_mfma_f32_16x16x32_bf16(w1f[ks][ms], zf, az[ms], 0, 0, 0);
            }
#pragma unroll
            for (int ms = 0; ms < 2; ++ms) {
                const int rb = r0 + (ms << 4);
                float hh[4], dd[4];
#pragma unroll
                for (int rg = 0; rg < 4; ++rg) {
                    float h = ftanh(az[ms][rg] + b1l[rb + rg]);
                    hh[rg] = h; dd[rg] = 1.f - h * h;
                }
                if (lm < 2) {
                    *(float4*)&dvec1[lm * 256 + rb] = make_float4(dd[0], dd[1], dd[2], dd[3]);
                    uint2v hp; hp[0] = cvtpk(hh[0], hh[1]); hp[1] = cvtpk(hh[2], hh[3]);
                    *(uint2v*)&XT[(128 + lm) * 264 + rb] = hp;
                }
            }
        }
        __syncthreads();

        // ---- P2: build A1^T for both samples into XT rows 0-127 ----
        {
            const int i = tid >> 3, k0 = (tid & 7) << 5;
#pragma unroll
            for (int c = 0; c < 4; ++c) {
                const int kk = k0 + (c << 3);
                const bf16x8 wv = *(const bf16x8*)&W1T[i * 264 + kk];
                float wf[8];
#pragma unroll
                for (int q = 0; q < 8; ++q) wf[q] = bf2fs(wv[q]);
                const float4 a0 = *(const float4*)&dvec1[kk];
                const float4 a1 = *(const float4*)&dvec1[kk + 4];
                const float4 c0 = *(const float4*)&dvec1[256 + kk];
                const float4 c1 = *(const float4*)&dvec1[256 + kk + 4];
                uint4v oA, oB;
                oA[0] = cvtpk(wf[0] * a0.x, wf[1] * a0.y);
                oA[1] = cvtpk(wf[2] * a0.z, wf[3] * a0.w);
                oA[2] = cvtpk(wf[4] * a1.x, wf[5] * a1.y);
                oA[3] = cvtpk(wf[6] * a1.z, wf[7] * a1.w);
                oB[0] = cvtpk(wf[0] * c0.x, wf[1] * c0.y);
                oB[1] = cvtpk(wf[2] * c0.z, wf[3] * c0.w);
                oB[2] = cvtpk(wf[4] * c1.x, wf[5] * c1.y);
                oB[3] = cvtpk(wf[6] * c1.z, wf[7] * c1.w);
                *(uint4v*)&XT[i * 264 + kk] = oA;
                *(uint4v*)&XT[(64 + i) * 264 + kk] = oB;
            }
        }
        __syncthreads();

        // ---- P3: GEMM1 pass A (s0 tiles + h1 parity tile) ----
        ZERO5();
        GEMM_PASS_A(w2f, 128)
        __syncthreads();

        // ---- P4: epi2-A (h2 both samples, A2_s0 scale-write) + GEMM1 pass B ----
        {
#pragma unroll
            for (int ms = 0; ms < 2; ++ms) {
                const int rb = r0 + (ms << 4);
                float hh[4];
#pragma unroll
                for (int rg = 0; rg < 4; ++rg) {
                    float h = ftanh(acc[ms][4][rg] + b2l[rb + rg]);
                    hh[rg] = h; d2loc[ms][rg] = 1.f - h * h;
                }
                if (lm < 2) {
                    uint2v hp; hp[0] = cvtpk(hh[0], hh[1]); hp[1] = cvtpk(hh[2], hh[3]);
                    *(uint2v*)&XT[(130 + lm) * 264 + rb] = hp;
                }
            }
#pragma unroll
            for (int ms = 0; ms < 2; ++ms) {
                const int rb = r0 + (ms << 4);
                float ds[4];
#pragma unroll
                for (int rg = 0; rg < 4; ++rg) ds[rg] = __shfl(d2loc[ms][rg], l & 48, 64);
#pragma unroll
                for (int ns = 0; ns < 4; ++ns) {
                    uint2v o;
                    o[0] = cvtpk(acc[ms][ns][0] * ds[0], acc[ms][ns][1] * ds[1]);
                    o[1] = cvtpk(acc[ms][ns][2] * ds[2], acc[ms][ns][3] * ds[3]);
                    *(uint2v*)&XT[((ns << 4) + lm) * 264 + rb] = o;
                }
            }
            ZERO4();
            GEMM_PASS_B(w2f)
        }
        __syncthreads();

        // ---- P5: epi2-B (A2_s1 scale-write) + GEMM2 pass A ----
        {
#pragma unroll
            for (int ms = 0; ms < 2; ++ms) {
                const int rb = r0 + (ms << 4);
                float ds[4];
#pragma unroll
                for (int rg = 0; rg < 4; ++rg) ds[rg] = __shfl(d2loc[ms][rg], (l & 48) + 1, 64);
#pragma unroll
                for (int ns = 0; ns < 4; ++ns) {
                    uint2v o;
                    o[0] = cvtpk(acc[ms][ns][0] * ds[0], acc[ms][ns][1] * ds[1]);
                    o[1] = cvtpk(acc[ms][ns][2] * ds[2], acc[ms][ns][3] * ds[3]);
                    *(uint2v*)&XT[(((ns + 4) << 4) + lm) * 264 + rb] = o;
                }
            }
            ZERO5();
            GEMM_PASS_A(w3f, 130)
        }
        __syncthreads();

        // ---- P6: epi3-A (h3/d3 both samples, div partial s0) + GEMM2 pass B ----
        {
#pragma unroll
            for (int ms = 0; ms < 2; ++ms) {
                const int rb = r0 + (ms << 4);
                float hh[4];
#pragma unroll
                for (int rg = 0; rg < 4; ++rg) {
                    float h = ftanh(acc[ms][4][rg] + b3l[rb + rg]);
                    hh[rg] = h; d3loc[ms][rg] = 1.f - h * h;
                }
                if (lm < 2) *(float4*)&hvec[lm * 256 + rb] = make_float4(hh[0], hh[1], hh[2], hh[3]);
            }
            p0 = 0.f;
#pragma unroll
            for (int ms = 0; ms < 2; ++ms) {
                const int rb = r0 + (ms << 4);
                float ds[4];
#pragma unroll
                for (int rg = 0; rg < 4; ++rg) ds[rg] = __shfl(d3loc[ms][rg], l & 48, 64);
#pragma unroll
                for (int ns = 0; ns < 4; ++ns) {
                    const short4v wv = *(const short4v*)&W4L[((ns << 4) + lm) * 264 + rb];
                    p0 += acc[ms][ns][0] * ds[0] * bf2fs(wv[0]);
                    p0 += acc[ms][ns][1] * ds[1] * bf2fs(wv[1]);
                    p0 += acc[ms][ns][2] * ds[2] * bf2fs(wv[2]);
                    p0 += acc[ms][ns][3] * ds[3] * bf2fs(wv[3]);
                }
            }
            ZERO4();
            GEMM_PASS_B(w3f)
        }
        __syncthreads();

        // ---- P7: epi3-B (div partial s1), div reduce, dz matvec ----
        {
            float p1 = 0.f;
#pragma unroll
            for (int ms = 0; ms < 2; ++ms) {
                const int rb = r0 + (ms << 4);
                float ds[4];
#pragma unroll
                for (int rg = 0; rg < 4; ++rg) ds[rg] = __shfl(d3loc[ms][rg], (l & 48) + 1, 64);
#pragma unroll
                for (int ns = 0; ns < 4; ++ns) {
                    // W4 column index is the latent index n = (ns<<4)+lm for BOTH
                    // samples — only XT's tangent storage is offset by 64 for s1.
                    const short4v wv = *(const short4v*)&W4L[((ns << 4) + lm) * 264 + rb];
                    p1 += acc[ms][ns][0] * ds[0] * bf2fs(wv[0]);
                    p1 += acc[ms][ns][1] * ds[1] * bf2fs(wv[1]);
                    p1 += acc[ms][ns][2] * ds[2] * bf2fs(wv[2]);
                    p1 += acc[ms][ns][3] * ds[3] * bf2fs(wv[3]);
                }
            }
#pragma unroll
            for (int o = 32; o; o >>= 1) {
                p0 += __shfl_xor(p0, o, 64);
                p1 += __shfl_xor(p1, o, 64);
            }
            if (l == 0) { wredp[w] = p0; wredp[8 + w] = p1; }
            // dz matvec: dz_s[i] partial over 64-k chunk
            {
                const int s = tid >> 8, ch = (tid >> 6) & 3, i = tid & 63;
                const unsigned short* wr = &W4L[i * 264 + (ch << 6)];
                const float* hv = &hvec[s * 256 + (ch << 6)];
                float a = 0.f;
#pragma unroll
                for (int c = 0; c < 8; ++c) {
                    bf16x8 wv = *(const bf16x8*)&wr[c * 8];
                    float4 h0 = *(const float4*)&hv[c * 8];
                    float4 h1 = *(const float4*)&hv[c * 8 + 4];
                    a += bf2fs(wv[0]) * h0.x + bf2fs(wv[1]) * h0.y + bf2fs(wv[2]) * h0.z + bf2fs(wv[3]) * h0.w;
                    a += bf2fs(wv[4]) * h1.x + bf2fs(wv[5]) * h1.y + bf2fs(wv[6]) * h1.z + bf2fs(wv[7]) * h1.w;
                }
                dzp[s * 256 + (ch << 6) + i] = a;
            }
        }
        __syncthreads();

        // ---- P8: RK bookkeeping (both samples) ----
        if (tid < 128) {
            const int s = tid >> 6, i = tid & 63;
            float div = 0.f;
#pragma unroll
            for (int wi = 0; wi < 8; ++wi) div += wredp[s * 8 + wi];
            float dz = dzp[s * 256 + i] + dzp[s * 256 + 64 + i] +
                       dzp[s * 256 + 128 + i] + dzp[s * 256 + 192 + i] + b4l[i];
            const float wgt = (e == 0 || e == 3) ? 1.f : 2.f;
            float kv = (e == 0) ? dz : kav[tid] + wgt * dz;
            kav[tid] = kv;
            float znew;
            if (e < 3) {
                const float cc = (e == 2) ? 1.0f : 0.5f;
                znew = zbv[tid] + cc * DT * dz;
            } else {
                znew = zbv[tid] + (DT / 6.0f) * kv;
                zbv[tid] = znew;
            }
            ZBT[s * 72 + i] = f2bf(znew);
            if (i == 0) {
                float klv = -div;
                float kl = (e == 0) ? klv : misc[s] + wgt * klv;
                misc[s] = kl;
                if (e == 3) misc[2 + s] += (DT / 6.0f) * kl;
            }
        }
        __syncthreads();
    }

    if (tid < 128) {
        const int s = tid >> 6, i = tid & 63;
        out[(bid * 2 + s) * 64 + i] = zbv[tid];
        if (i == 0) out[NSAMP * 64 + bid * 2 + s] = misc[2 + s];
    }
}

extern "C" void kernel_launch(void* const* d_in, const int* in_sizes, int n_in,
                              void* d_out, int out_size, void* d_ws, size_t ws_size,
                              hipStream_t stream) {
    const float* z  = (const float*)d_in[0];
    const float* W1 = (const float*)d_in[1];
    const float* b1 = (const float*)d_in[2];
    const float* W2 = (const float*)d_in[3];
    const float* b2 = (const float*)d_in[4];
    const float* W3 = (const float*)d_in[5];
    const float* b3 = (const float*)d_in[6];
    const float* W4 = (const float*)d_in[7];
    const float* b4 = (const float*)d_in[8];
    unsigned short* ws = (unsigned short*)d_ws;
    float* out = (float*)d_out;

    hipLaunchKernelGGL(prep_kernel, dim3(256), dim3(256), 0, stream, W1, W2, W3, W4, ws);
    hipLaunchKernelGGL(cnf_kernel, dim3(NSAMP / 2), dim3(512), 0, stream, z, b1, b2, b3, b4, ws, out);
}